// Round 5
// baseline (103679.150 us; speedup 1.0000x reference)
//
#include <hip/hip_runtime.h>

// NCDE classifier: B=512 chains, T=2048 steps, D=32, M=64, W=128.
// Round-4 design: 64 INDEPENDENT blocks x 8 chains. No inter-block sync.
// Per RK4 stage each block re-streams full W2 (f16, frag-linear in d_ws)
// from L2 directly into MFMA B-fragments. W0/W1 live in registers.

#define TT   2048
#define NTH  512
#define NCH  8

typedef _Float16 f16;
typedef _Float16 f16x8 __attribute__((ext_vector_type(8)));
typedef float f32x4 __attribute__((ext_vector_type(4)));

// LDS byte offsets (static shared, 30720 B total)
#define O_DTS 0        // 2047 f32 (padded to 8192)
#define O_YIN 8192     // [16][64] f16, swizzled 128B rows : 2048
#define O_H1  10240    // [16][128] f16, swizzled 256B rows : 4096
#define O_H2  14336    // [16][128] f16 : 4096
#define O_GS  18432    // [8][64] f32 : 2048
#define O_DX  20480    // [8][32] f32 : 1024 (also x0 scratch in encoder)
#define O_B2  21504    // 2048 f32 : 8192
#define O_B0  29696    // 128 f32
#define O_B1  30208    // 128 f32
#define LDS_TOT 30720

__device__ __forceinline__ float tanh_fast(float x){
    float e = __expf(2.0f * x);
    return 1.0f - 2.0f * __builtin_amdgcn_rcpf(e + 1.0f);
}
__device__ __forceinline__ float gelu_f(float x){
    float u = x + 0.044715f * x * x * x;
    return 0.5f * x * (1.0f + tanh_fast(0.7978845608028654f * u));
}

// Load the 4 K-fragments of one 16-col W2 tile into registers (B-operand).
template<bool F16>
__device__ __forceinline__ void load_tile_frags(f16x8* buf, const f16* w2r,
                                                const float* vW2, int tl, int l){
    if constexpr (F16){
        const f16* base = w2r + (size_t)tl*2048 + l*8;   // frag-linear layout
        #pragma unroll
        for (int kf = 0; kf < 4; ++kf)
            buf[kf] = *(const f16x8*)(base + kf*512);
    } else {
        int n = tl*16 + (l & 15);
        int k0 = (l >> 4) << 3;
        #pragma unroll
        for (int kf = 0; kf < 4; ++kf){
            const float* p = vW2 + n*128 + kf*32 + k0;
            float4 u = *(const float4*)p;
            float4 v2 = *(const float4*)(p + 4);
            f16x8 t;
            t[0]=(f16)u.x; t[1]=(f16)u.y; t[2]=(f16)u.z; t[3]=(f16)u.w;
            t[4]=(f16)v2.x; t[5]=(f16)v2.y; t[6]=(f16)v2.z; t[7]=(f16)v2.w;
            buf[kf] = t;
        }
    }
}

// Pre-pass: W2 f32 [2048][128] -> frag-linear f16: idx = ((tl*4+kf)*64+l)*8+i
__global__ void __launch_bounds__(512) reorder_w2(const float* __restrict__ vW2,
                                                  f16* __restrict__ w2r){
    int idx = blockIdx.x * 512 + threadIdx.x;     // grid 512 -> 262144
    int i  = idx & 7;
    int l  = (idx >> 3) & 63;
    int kf = (idx >> 9) & 3;
    int tl = idx >> 11;
    int n = tl*16 + (l & 15);
    int k = kf*32 + ((l >> 4) << 3) + i;
    w2r[idx] = (f16)vW2[n*128 + k];
}

template<bool F16>
__global__ void __launch_bounds__(NTH, 1)
ncde_main(const float* __restrict__ times, const float* __restrict__ xs,
          const float* __restrict__ eW0, const float* __restrict__ eb0,
          const float* __restrict__ eW1, const float* __restrict__ eb1,
          const float* __restrict__ eW2, const float* __restrict__ eb2,
          const float* __restrict__ vW0, const float* __restrict__ vW1,
          const float* __restrict__ vb0, const float* __restrict__ vb1,
          const float* __restrict__ vW2, const float* __restrict__ vb2,
          const float* __restrict__ dW, const float* __restrict__ db,
          const f16* __restrict__ w2r, float* __restrict__ out)
{
    __shared__ __align__(16) char lds[LDS_TOT];
    float* dtsf = (float*)(lds + O_DTS);
    float* gsf  = (float*)(lds + O_GS);
    float* dxf  = (float*)(lds + O_DX);
    float* b2s  = (float*)(lds + O_B2);
    float* b0f  = (float*)(lds + O_B0);
    float* b1f  = (float*)(lds + O_B1);
    float* enc1f= (float*)(lds + O_H1);   // encoder scratch (aliases H1)
    float* enc2f= (float*)(lds + O_H2);   // encoder scratch (aliases H2)

    const int tid = threadIdx.x;
    const int l   = tid & 63;
    const int w   = tid >> 6;            // wave 0..7
    const int c0  = blockIdx.x * NCH;    // first chain of this block

    // ---- one-time LDS fills ----
    for (int i = tid; i < 2047; i += NTH) dtsf[i] = times[i+1] - times[i];
    for (int i = tid; i < 2048; i += NTH) b2s[i] = vb2[i];
    if (tid < 128){ b0f[tid] = vb0[tid]; b1f[tid] = vb1[tid]; }

    // per-owner x regs (tid<256: r=tid>>5, d=tid&31)
    float xcur = 0.f, xn = 0.f;
    if (tid < 256){
        int r = tid >> 5, d = tid & 31;
        xcur = xs[((size_t)(c0 + r) * TT + 0) * 32 + d];
        xn   = xs[((size_t)(c0 + r) * TT + 1) * 32 + d];
        dxf[(tid >> 5)*32 + (tid & 31)] = xcur;   // x0 scratch for encoder
    }
    __syncthreads();

    // ---- encoder (8 chains) ----
    for (int i = tid; i < NCH*128; i += NTH){
        int r = i >> 7, n = i & 127;
        float a = eb0[n];
        #pragma unroll
        for (int k = 0; k < 32; ++k) a += eW0[n*32 + k] * dxf[r*32 + k];
        enc1f[i] = fmaxf(a, 0.f);
    }
    __syncthreads();
    for (int i = tid; i < NCH*128; i += NTH){
        int r = i >> 7, n = i & 127;
        float a = eb1[n];
        for (int k = 0; k < 128; ++k) a += eW1[n*128 + k] * enc1f[r*128 + k];
        enc2f[i] = fmaxf(a, 0.f);
    }
    __syncthreads();
    // y0 per owner thread: tid -> (r = tid>>6, m = tid&63)
    float yreg;
    {
        int r = tid >> 6, m = tid & 63;
        float a = eb2[m];
        for (int k = 0; k < 128; ++k) a += eW2[m*128 + k] * enc2f[r*128 + k];
        yreg = a;
    }
    __syncthreads();

    // ---- zero YIN/H1/H2 (rows 8-15 stay zero forever) ----
    for (int i = tid; i < (2048 + 4096 + 4096)/4; i += NTH)
        ((unsigned*)(lds + O_YIN))[i] = 0u;
    __syncthreads();
    // write y0 into YIN rows 0-7 (f16, swizzled)
    {
        int r = tid >> 6, m = tid & 63;
        *(f16*)(lds + O_YIN + r*128 + ((m*2) ^ ((r & 7) << 4))) = (f16)yreg;
    }

    // ---- W0/W1 register B-fragments (col = w*16 + (l&15)) ----
    f16x8 w0f[2], w1f[4];
    {
        int col  = w*16 + (l & 15);
        int krow = (l >> 4) << 3;
        #pragma unroll
        for (int ks = 0; ks < 2; ++ks){
            const float* p = vW0 + col*64 + ks*32 + krow;
            f16x8 v;
            #pragma unroll
            for (int i = 0; i < 8; ++i) v[i] = (f16)p[i];
            w0f[ks] = v;
        }
        #pragma unroll
        for (int ks = 0; ks < 4; ++ks){
            const float* p = vW1 + col*128 + ks*32 + krow;
            f16x8 v;
            #pragma unroll
            for (int i = 0; i < 8; ++i) v[i] = (f16)p[i];
            w1f[ks] = v;
        }
    }
    __syncthreads();

    const int arow = l & 15;
    const int g    = l >> 4;            // 16-lane group 0..3

    for (int t = 0; t < TT-1; ++t){
        float dtv = dtsf[t];
        // owners: dxdt write + prefetch xs[t+2]
        float xf = 0.f;
        if (tid < 256){
            int r = tid >> 5, d = tid & 31;
            if (t + 2 < TT) xf = xs[((size_t)(c0 + r) * TT + (t+2)) * 32 + d];
            dxf[r*32 + d] = (xn - xcur) / dtv;
            xcur = xn;
        }
        float ka = 0.f;

        #pragma unroll 1
        for (int st = 0; st < 4; ++st){
            // prefetch first W2 tile pair of this wave's stream
            f16x8 cbe[4], cbo[4], nbe[4], nbo[4];
            load_tile_frags<F16>(cbe, w2r, vW2, w*16 + 0, l);
            load_tile_frags<F16>(cbo, w2r, vW2, w*16 + 1, l);

            // ---- L1: yin(8x64) @ W0^T -> h1, gelu ----
            {
                f32x4 acc = {0.f,0.f,0.f,0.f};
                #pragma unroll
                for (int kf = 0; kf < 2; ++kf){
                    f16x8 a = *(const f16x8*)(lds + O_YIN + arow*128 +
                               ((kf*64 + g*16) ^ ((arow & 7) << 4)));
                    acc = __builtin_amdgcn_mfma_f32_16x16x32_f16(a, w0f[kf], acc, 0, 0, 0);
                }
                if (g < 2){
                    int col = w*16 + (l & 15);
                    float bb = b0f[col];
                    #pragma unroll
                    for (int j = 0; j < 4; ++j){
                        int row = g*4 + j;
                        float gg = gelu_f(acc[j] + bb);
                        *(f16*)(lds + O_H1 + row*256 + ((col*2) ^ ((row & 7) << 4))) = (f16)gg;
                    }
                }
            }
            __syncthreads();
            // ---- L2: h1 @ W1^T -> h2, gelu ----
            {
                f32x4 acc = {0.f,0.f,0.f,0.f};
                #pragma unroll
                for (int kf = 0; kf < 4; ++kf){
                    f16x8 a = *(const f16x8*)(lds + O_H1 + arow*256 +
                               ((kf*64 + g*16) ^ ((arow & 7) << 4)));
                    acc = __builtin_amdgcn_mfma_f32_16x16x32_f16(a, w1f[kf], acc, 0, 0, 0);
                }
                if (g < 2){
                    int col = w*16 + (l & 15);
                    float bb = b1f[col];
                    #pragma unroll
                    for (int j = 0; j < 4; ++j){
                        int row = g*4 + j;
                        float gg = gelu_f(acc[j] + bb);
                        *(f16*)(lds + O_H2 + row*256 + ((col*2) ^ ((row & 7) << 4))) = (f16)gg;
                    }
                }
            }
            __syncthreads();
            // ---- L3: h2 @ W2^T streamed; tanh * dXdt; reduce -> gs[r][m] ----
            {
                f16x8 a3[4];
                #pragma unroll
                for (int kf = 0; kf < 4; ++kf)
                    a3[kf] = *(const f16x8*)(lds + O_H2 + arow*256 +
                              ((kf*64 + g*16) ^ ((arow & 7) << 4)));

                #pragma unroll
                for (int p = 0; p < 8; ++p){
                    if (p < 7){
                        load_tile_frags<F16>(nbe, w2r, vW2, w*16 + 2*(p+1),     l);
                        load_tile_frags<F16>(nbo, w2r, vW2, w*16 + 2*(p+1) + 1, l);
                    }
                    f32x4 ae = {0.f,0.f,0.f,0.f}, ao = {0.f,0.f,0.f,0.f};
                    #pragma unroll
                    for (int kf = 0; kf < 4; ++kf){
                        ae = __builtin_amdgcn_mfma_f32_16x16x32_f16(a3[kf], cbe[kf], ae, 0, 0, 0);
                        ao = __builtin_amdgcn_mfma_f32_16x16x32_f16(a3[kf], cbo[kf], ao, 0, 0, 0);
                    }
                    // epilogue for tile pair p  (m = w*8 + p)
                    {
                        int c   = l & 15;
                        float be = b2s[(w*16 + 2*p)*16 + c];
                        float bo = b2s[(w*16 + 2*p + 1)*16 + c];
                        #pragma unroll
                        for (int j = 0; j < 4; ++j){
                            int rr = (g*4 + j) & 7;
                            float de = dxf[rr*32 + c];
                            float dd = dxf[rr*32 + 16 + c];
                            float pe = tanh_fast(ae[j] + be) * de
                                     + tanh_fast(ao[j] + bo) * dd;
                            pe += __shfl_xor(pe, 1);
                            pe += __shfl_xor(pe, 2);
                            pe += __shfl_xor(pe, 4);
                            pe += __shfl_xor(pe, 8);
                            if (g < 2 && c == p)
                                gsf[(g*4 + j)*64 + w*8 + p] = pe;
                        }
                    }
                    #pragma unroll
                    for (int kf = 0; kf < 4; ++kf){ cbe[kf] = nbe[kf]; cbo[kf] = nbo[kf]; }
                }
            }
            __syncthreads();
            // ---- owner RK4 update: tid -> (r = tid>>6, m = tid&63) ----
            {
                int r = tid >> 6, m = tid & 63;
                float kv = gsf[tid];
                float wgt = (st == 1 || st == 2) ? 2.f : 1.f;
                ka += wgt * kv;
                float yst;
                if (st < 3){
                    float cs = (st == 2) ? 1.0f : 0.5f;
                    yst = yreg + cs * dtv * kv;
                } else {
                    yreg = yreg + (dtv * (1.0f/6.0f)) * ka;
                    yst = yreg;
                }
                *(f16*)(lds + O_YIN + r*128 + ((m*2) ^ ((r & 7) << 4))) = (f16)yst;
            }
            __syncthreads();
        } // stages
        if (tid < 256) xn = xf;
    } // t

    // ---- decoder: logit[r] = sum_m y[r][m]*dW[m] + db; sigmoid ----
    gsf[tid] = yreg * dW[tid & 63];
    __syncthreads();
    if (tid < NCH){
        float a = db[0];
        for (int m = 0; m < 64; ++m) a += gsf[tid*64 + m];
        out[c0 + tid] = 1.0f / (1.0f + __expf(-a));
    }
}

extern "C" void kernel_launch(void* const* d_in, const int* in_sizes, int n_in,
                              void* d_out, int out_size, void* d_ws, size_t ws_size,
                              hipStream_t stream)
{
    const float* times = (const float*)d_in[0];
    const float* xs    = (const float*)d_in[1];
    const float* eW0   = (const float*)d_in[2];
    const float* eb0   = (const float*)d_in[3];
    const float* eW1   = (const float*)d_in[4];
    const float* eb1   = (const float*)d_in[5];
    const float* eW2   = (const float*)d_in[6];
    const float* eb2   = (const float*)d_in[7];
    const float* vW0   = (const float*)d_in[8];
    const float* vb0   = (const float*)d_in[9];
    const float* vW1   = (const float*)d_in[10];
    const float* vb1   = (const float*)d_in[11];
    const float* vW2   = (const float*)d_in[12];
    const float* vb2   = (const float*)d_in[13];
    const float* dW    = (const float*)d_in[14];
    const float* db    = (const float*)d_in[15];

    const size_t w2_bytes = (size_t)2048 * 128 * sizeof(f16);   // 512 KB
    if (ws_size >= w2_bytes){
        f16* w2r = (f16*)d_ws;
        reorder_w2<<<dim3(512), dim3(512), 0, stream>>>(vW2, w2r);
        ncde_main<true><<<dim3(64), dim3(NTH), 0, stream>>>(
            times, xs, eW0, eb0, eW1, eb1, eW2, eb2,
            vW0, vW1, vb0, vb1, vW2, vb2, dW, db,
            (const f16*)w2r, (float*)d_out);
    } else {
        ncde_main<false><<<dim3(64), dim3(NTH), 0, stream>>>(
            times, xs, eW0, eb0, eW1, eb1, eW2, eb2,
            vW0, vW1, vb0, vb1, vW2, vb2, dW, db,
            (const f16*)nullptr, (float*)d_out);
    }
}

// Round 6
// 81283.167 us; speedup vs baseline: 1.2755x; 1.2755x over previous
//
#include <hip/hip_runtime.h>

// NCDE classifier: B=512 chains, T=2048 steps, D=32, M=64, W=128.
// Round-6: 64 independent blocks x 8 chains, 1 block/CU, 8 waves.
// W2 (128 tiles of 16 cols x 128 k, f16 frag-linear): per wave 16 tiles ->
//   2 pairs in REGISTERS + 2 pairs in LDS (128 KB) + 4 pairs STREAMED from L2
//   (256 KB/stage, deep-prefetched). W0/W1 in registers. No inter-block sync.

#define TT   2048
#define NTH  512
#define NCH  8
#define R_P  2   // register-resident tile-pairs per wave
#define L_P  2   // LDS-resident tile-pairs per wave

typedef _Float16 f16;
typedef _Float16 f16x8 __attribute__((ext_vector_type(8)));
typedef float f32x4 __attribute__((ext_vector_type(4)));

// dynamic LDS layout (bytes)
#define O_W2L 0         // 32 tiles * 4096 B = 131072 (frag-linear, per-wave slots)
#define O_DTS 131072    // 2047 f32 (padded 8192)
#define O_B2  139264    // 2048 f32 = 8192
#define O_H1  147456    // [16][128] f16 swizzled = 4096 (also encoder scratch)
#define O_H2  151552    // 4096 (also encoder scratch)
#define O_YIN 155648    // [16][64] f16 swizzled = 2048
#define O_GS  157696    // [8][64] f32 = 2048
#define O_DX  159744    // [8][32] f32 = 1024
#define O_B0  160768    // 128 f32
#define O_B1  161280    // 128 f32
#define LDSB  161792

__device__ __forceinline__ float tanh_fast(float x){
    float e = __expf(2.0f * x);
    return 1.0f - 2.0f * __builtin_amdgcn_rcpf(e + 1.0f);
}
__device__ __forceinline__ float gelu_f(float x){
    float u = x + 0.044715f * x * x * x;
    return 0.5f * x * (1.0f + tanh_fast(0.7978845608028654f * u));
}

// Load 4 K-fragments of one 16-col W2 tile into regs (MFMA B-operand).
template<bool F16>
__device__ __forceinline__ void load_tile_frags(f16x8* buf, const f16* w2r,
                                                const float* vW2, int tl, int l){
    if constexpr (F16){
        const f16* base = w2r + (size_t)tl*2048 + l*8;   // frag-linear
        #pragma unroll
        for (int kf = 0; kf < 4; ++kf)
            buf[kf] = *(const f16x8*)(base + kf*512);
    } else {
        int n = tl*16 + (l & 15);
        int k0 = (l >> 4) << 3;
        #pragma unroll
        for (int kf = 0; kf < 4; ++kf){
            const float* p = vW2 + n*128 + kf*32 + k0;
            float4 u = *(const float4*)p;
            float4 v2 = *(const float4*)(p + 4);
            f16x8 t;
            t[0]=(f16)u.x; t[1]=(f16)u.y; t[2]=(f16)u.z; t[3]=(f16)u.w;
            t[4]=(f16)v2.x; t[5]=(f16)v2.y; t[6]=(f16)v2.z; t[7]=(f16)v2.w;
            buf[kf] = t;
        }
    }
}

// Issue both tiles of stream pair p into register buffers.
template<bool F16>
__device__ __forceinline__ void issue_pair(f16x8* de, f16x8* dob, const f16* w2r,
                                           const float* vW2, int w, int p, int l){
    if constexpr (F16){
        const f16* be = w2r + ((size_t)(w*16 + 2*p))*2048 + l*8;
        #pragma unroll
        for (int kf = 0; kf < 4; ++kf){
            de[kf]  = *(const f16x8*)(be + kf*512);
            dob[kf] = *(const f16x8*)(be + 2048 + kf*512);
        }
    } else {
        load_tile_frags<false>(de,  nullptr, vW2, w*16 + 2*p,     l);
        load_tile_frags<false>(dob, nullptr, vW2, w*16 + 2*p + 1, l);
    }
}

// Pre-pass: W2 f32 [2048][128] -> frag-linear f16: idx = ((tl*4+kf)*64+l)*8+i
__global__ void __launch_bounds__(512) reorder_w2(const float* __restrict__ vW2,
                                                  f16* __restrict__ w2r){
    int idx = blockIdx.x * 512 + threadIdx.x;     // grid 512 -> 262144
    int i  = idx & 7;
    int l  = (idx >> 3) & 63;
    int kf = (idx >> 9) & 3;
    int tl = idx >> 11;
    int n = tl*16 + (l & 15);
    int k = kf*32 + ((l >> 4) << 3) + i;
    w2r[idx] = (f16)vW2[n*128 + k];
}

template<bool F16>
__global__ void __launch_bounds__(NTH, 1)
ncde_main(const float* __restrict__ times, const float* __restrict__ xs,
          const float* __restrict__ eW0, const float* __restrict__ eb0,
          const float* __restrict__ eW1, const float* __restrict__ eb1,
          const float* __restrict__ eW2, const float* __restrict__ eb2,
          const float* __restrict__ vW0, const float* __restrict__ vW1,
          const float* __restrict__ vb0, const float* __restrict__ vb1,
          const float* __restrict__ vW2, const float* __restrict__ vb2,
          const float* __restrict__ dW, const float* __restrict__ db,
          const f16* __restrict__ w2r, float* __restrict__ out)
{
    extern __shared__ __align__(16) char lds[];
    float* dtsf = (float*)(lds + O_DTS);
    float* gsf  = (float*)(lds + O_GS);
    float* dxf  = (float*)(lds + O_DX);
    float* b2s  = (float*)(lds + O_B2);
    float* b0f  = (float*)(lds + O_B0);
    float* b1f  = (float*)(lds + O_B1);
    float* enc1f= (float*)(lds + O_H1);   // encoder scratch (pre-loop only)
    float* enc2f= (float*)(lds + O_H2);

    const int tid = threadIdx.x;
    const int l   = tid & 63;
    const int w   = tid >> 6;            // wave 0..7
    const int c0  = blockIdx.x * NCH;

    // ---- one-time LDS fills ----
    for (int i = tid; i < 2047; i += NTH) dtsf[i] = times[i+1] - times[i];
    for (int i = tid; i < 2048; i += NTH) b2s[i] = vb2[i];
    if (tid < 128){ b0f[tid] = vb0[tid]; b1f[tid] = vb1[tid]; }

    float xcur = 0.f, xn = 0.f;
    if (tid < 256){
        int r = tid >> 5, d = tid & 31;
        xcur = xs[((size_t)(c0 + r) * TT + 0) * 32 + d];
        xn   = xs[((size_t)(c0 + r) * TT + 1) * 32 + d];
        dxf[r*32 + d] = xcur;            // x0 scratch for encoder
    }
    __syncthreads();

    // ---- encoder (8 chains) ----
    for (int i = tid; i < NCH*128; i += NTH){
        int r = i >> 7, n = i & 127;
        float a = eb0[n];
        #pragma unroll
        for (int k = 0; k < 32; ++k) a += eW0[n*32 + k] * dxf[r*32 + k];
        enc1f[i] = fmaxf(a, 0.f);
    }
    __syncthreads();
    for (int i = tid; i < NCH*128; i += NTH){
        int r = i >> 7, n = i & 127;
        float a = eb1[n];
        for (int k = 0; k < 128; ++k) a += eW1[n*128 + k] * enc1f[r*128 + k];
        enc2f[i] = fmaxf(a, 0.f);
    }
    __syncthreads();
    float yreg;
    {
        int r = tid >> 6, m = tid & 63;
        float a = eb2[m];
        for (int k = 0; k < 128; ++k) a += eW2[m*128 + k] * enc2f[r*128 + k];
        yreg = a;
    }
    __syncthreads();

    // ---- zero H1/H2/YIN (contiguous 10240 B); fill LDS-resident W2 ----
    for (int i = tid; i < 10240/4; i += NTH)
        ((unsigned*)(lds + O_H1))[i] = 0u;
    if constexpr (F16){
        for (int i = tid; i < 8192; i += NTH){          // 16-B chunks
            int slot = i >> 8, b = (i & 255) << 4;
            int sw = slot >> 2, sp = (slot >> 1) & 1, se = slot & 1;
            int tl = sw*16 + 2*(R_P + sp) + se;
            *(f16x8*)(lds + O_W2L + slot*4096 + b) =
                *(const f16x8*)((const char*)w2r + (size_t)tl*4096 + b);
        }
    } else {
        for (int i = tid; i < 65536; i += NTH){
            int slot = i >> 11, elem = i & 2047;
            int sw = slot >> 2, sp = (slot >> 1) & 1, se = slot & 1;
            int tl = sw*16 + 2*(R_P + sp) + se;
            int kf = elem >> 9, rem = elem & 511, ll = rem >> 3, ii = rem & 7;
            int n = tl*16 + (ll & 15);
            int k = kf*32 + ((ll >> 4) << 3) + ii;
            *(f16*)(lds + O_W2L + slot*4096 + elem*2) = (f16)vW2[n*128 + k];
        }
    }
    __syncthreads();

    // write y0 into YIN rows 0-7 (f16, swizzled)
    {
        int r = tid >> 6, m = tid & 63;
        *(f16*)(lds + O_YIN + r*128 + ((m*2) ^ ((r & 7) << 4))) = (f16)yreg;
    }

    // ---- W0/W1 register B-fragments (col = w*16 + (l&15)) ----
    f16x8 w0f[2], w1f[4];
    {
        int col  = w*16 + (l & 15);
        int krow = (l >> 4) << 3;
        #pragma unroll
        for (int ks = 0; ks < 2; ++ks){
            const float* p = vW0 + col*64 + ks*32 + krow;
            f16x8 v;
            #pragma unroll
            for (int i = 0; i < 8; ++i) v[i] = (f16)p[i];
            w0f[ks] = v;
        }
        #pragma unroll
        for (int ks = 0; ks < 4; ++ks){
            const float* p = vW1 + col*128 + ks*32 + krow;
            f16x8 v;
            #pragma unroll
            for (int i = 0; i < 8; ++i) v[i] = (f16)p[i];
            w1f[ks] = v;
        }
    }
    // ---- register-resident W2 pairs 0..R_P-1 ----
    f16x8 rw2[R_P][2][4];
    #pragma unroll
    for (int p = 0; p < R_P; ++p)
        #pragma unroll
        for (int e = 0; e < 2; ++e)
            load_tile_frags<F16>(rw2[p][e], w2r, vW2, w*16 + 2*p + e, l);
    __syncthreads();

    const int arow = l & 15;
    const int g    = l >> 4;

    for (int t = 0; t < TT-1; ++t){
        float dtv = dtsf[t];
        float xf = 0.f;
        if (tid < 256){
            int r = tid >> 5, d = tid & 31;
            if (t + 2 < TT) xf = xs[((size_t)(c0 + r) * TT + (t+2)) * 32 + d];
            dxf[r*32 + d] = (xn - xcur) / dtv;
            xcur = xn;
        }
        float ka = 0.f;

        #pragma unroll 1
        for (int st = 0; st < 4; ++st){
            // deep prefetch: stream pairs 4 and 5 issued at stage top
            f16x8 sAe[4], sAo[4], sBe[4], sBo[4];
            issue_pair<F16>(sAe, sAo, w2r, vW2, w, 4, l);
            issue_pair<F16>(sBe, sBo, w2r, vW2, w, 5, l);

            // ---- L1: yin @ W0^T -> h1, gelu ----
            {
                f32x4 acc = {0.f,0.f,0.f,0.f};
                #pragma unroll
                for (int kf = 0; kf < 2; ++kf){
                    f16x8 a = *(const f16x8*)(lds + O_YIN + arow*128 +
                               ((kf*64 + g*16) ^ ((arow & 7) << 4)));
                    acc = __builtin_amdgcn_mfma_f32_16x16x32_f16(a, w0f[kf], acc, 0, 0, 0);
                }
                if (g < 2){
                    int col = w*16 + (l & 15);
                    float bb = b0f[col];
                    #pragma unroll
                    for (int j = 0; j < 4; ++j){
                        int row = g*4 + j;
                        float gg = gelu_f(acc[j] + bb);
                        *(f16*)(lds + O_H1 + row*256 + ((col*2) ^ ((row & 7) << 4))) = (f16)gg;
                    }
                }
            }
            __syncthreads();
            // ---- L2: h1 @ W1^T -> h2, gelu ----
            {
                f32x4 acc = {0.f,0.f,0.f,0.f};
                #pragma unroll
                for (int kf = 0; kf < 4; ++kf){
                    f16x8 a = *(const f16x8*)(lds + O_H1 + arow*256 +
                               ((kf*64 + g*16) ^ ((arow & 7) << 4)));
                    acc = __builtin_amdgcn_mfma_f32_16x16x32_f16(a, w1f[kf], acc, 0, 0, 0);
                }
                if (g < 2){
                    int col = w*16 + (l & 15);
                    float bb = b1f[col];
                    #pragma unroll
                    for (int j = 0; j < 4; ++j){
                        int row = g*4 + j;
                        float gg = gelu_f(acc[j] + bb);
                        *(f16*)(lds + O_H2 + row*256 + ((col*2) ^ ((row & 7) << 4))) = (f16)gg;
                    }
                }
            }
            __syncthreads();
            // ---- L3: h2 @ W2^T (reg/LDS/stream tiles); tanh * dXdt; reduce ----
            {
                f16x8 a3[4];
                #pragma unroll
                for (int kf = 0; kf < 4; ++kf)
                    a3[kf] = *(const f16x8*)(lds + O_H2 + arow*256 +
                              ((kf*64 + g*16) ^ ((arow & 7) << 4)));

                #pragma unroll
                for (int p = 0; p < 8; ++p){
                    f16x8 fe[4], fo[4];
                    if (p < R_P){
                        #pragma unroll
                        for (int kf = 0; kf < 4; ++kf){ fe[kf] = rw2[p][0][kf]; fo[kf] = rw2[p][1][kf]; }
                    } else if (p < R_P + L_P){
                        int slotb = O_W2L + (w*4 + (p - R_P)*2) * 4096 + l*16;
                        #pragma unroll
                        for (int kf = 0; kf < 4; ++kf){
                            fe[kf] = *(const f16x8*)(lds + slotb + kf*1024);
                            fo[kf] = *(const f16x8*)(lds + slotb + 4096 + kf*1024);
                        }
                    } else if (p == 4 || p == 6){
                        #pragma unroll
                        for (int kf = 0; kf < 4; ++kf){ fe[kf] = sAe[kf]; fo[kf] = sAo[kf]; }
                    } else {
                        #pragma unroll
                        for (int kf = 0; kf < 4; ++kf){ fe[kf] = sBe[kf]; fo[kf] = sBo[kf]; }
                    }
                    f32x4 ae = {0.f,0.f,0.f,0.f}, ao = {0.f,0.f,0.f,0.f};
                    #pragma unroll
                    for (int kf = 0; kf < 4; ++kf){
                        ae = __builtin_amdgcn_mfma_f32_16x16x32_f16(a3[kf], fe[kf], ae, 0, 0, 0);
                        ao = __builtin_amdgcn_mfma_f32_16x16x32_f16(a3[kf], fo[kf], ao, 0, 0, 0);
                    }
                    if (p == 4) issue_pair<F16>(sAe, sAo, w2r, vW2, w, 6, l);
                    if (p == 5) issue_pair<F16>(sBe, sBo, w2r, vW2, w, 7, l);
                    // epilogue for pair p  (m = w*8 + p)
                    {
                        int c   = l & 15;
                        float be = b2s[(w*16 + 2*p)*16 + c];
                        float bo = b2s[(w*16 + 2*p + 1)*16 + c];
                        #pragma unroll
                        for (int j = 0; j < 4; ++j){
                            int rr = (g*4 + j) & 7;
                            float de = dxf[rr*32 + c];
                            float dd = dxf[rr*32 + 16 + c];
                            float pe = tanh_fast(ae[j] + be) * de
                                     + tanh_fast(ao[j] + bo) * dd;
                            pe += __shfl_xor(pe, 1);
                            pe += __shfl_xor(pe, 2);
                            pe += __shfl_xor(pe, 4);
                            pe += __shfl_xor(pe, 8);
                            if (g < 2 && c == p)
                                gsf[(g*4 + j)*64 + w*8 + p] = pe;
                        }
                    }
                }
            }
            __syncthreads();
            // ---- owner RK4 update: tid -> (r = tid>>6, m = tid&63) ----
            {
                int r = tid >> 6, m = tid & 63;
                float kv = gsf[tid];
                float wgt = (st == 1 || st == 2) ? 2.f : 1.f;
                ka += wgt * kv;
                float yst;
                if (st < 3){
                    float cs = (st == 2) ? 1.0f : 0.5f;
                    yst = yreg + cs * dtv * kv;
                } else {
                    yreg = yreg + (dtv * (1.0f/6.0f)) * ka;
                    yst = yreg;
                }
                *(f16*)(lds + O_YIN + r*128 + ((m*2) ^ ((r & 7) << 4))) = (f16)yst;
            }
            __syncthreads();
        } // stages
        if (tid < 256) xn = xf;
    } // t

    // ---- decoder ----
    gsf[tid] = yreg * dW[tid & 63];
    __syncthreads();
    if (tid < NCH){
        float a = db[0];
        for (int m = 0; m < 64; ++m) a += gsf[tid*64 + m];
        out[c0 + tid] = 1.0f / (1.0f + __expf(-a));
    }
}

extern "C" void kernel_launch(void* const* d_in, const int* in_sizes, int n_in,
                              void* d_out, int out_size, void* d_ws, size_t ws_size,
                              hipStream_t stream)
{
    const float* times = (const float*)d_in[0];
    const float* xs    = (const float*)d_in[1];
    const float* eW0   = (const float*)d_in[2];
    const float* eb0   = (const float*)d_in[3];
    const float* eW1   = (const float*)d_in[4];
    const float* eb1   = (const float*)d_in[5];
    const float* eW2   = (const float*)d_in[6];
    const float* eb2   = (const float*)d_in[7];
    const float* vW0   = (const float*)d_in[8];
    const float* vb0   = (const float*)d_in[9];
    const float* vW1   = (const float*)d_in[10];
    const float* vb1   = (const float*)d_in[11];
    const float* vW2   = (const float*)d_in[12];
    const float* vb2   = (const float*)d_in[13];
    const float* dW    = (const float*)d_in[14];
    const float* db    = (const float*)d_in[15];

    const size_t w2_bytes = (size_t)2048 * 128 * sizeof(f16);   // 512 KB
    if (ws_size >= w2_bytes){
        f16* w2r = (f16*)d_ws;
        reorder_w2<<<dim3(512), dim3(512), 0, stream>>>(vW2, w2r);
        hipFuncSetAttribute((const void*)ncde_main<true>,
                            hipFuncAttributeMaxDynamicSharedMemorySize, LDSB);
        ncde_main<true><<<dim3(64), dim3(NTH), LDSB, stream>>>(
            times, xs, eW0, eb0, eW1, eb1, eW2, eb2,
            vW0, vW1, vb0, vb1, vW2, vb2, dW, db,
            (const f16*)w2r, (float*)d_out);
    } else {
        hipFuncSetAttribute((const void*)ncde_main<false>,
                            hipFuncAttributeMaxDynamicSharedMemorySize, LDSB);
        ncde_main<false><<<dim3(64), dim3(NTH), LDSB, stream>>>(
            times, xs, eW0, eb0, eW1, eb1, eW2, eb2,
            vW0, vW1, vb0, vb1, vW2, vb2, dW, db,
            (const f16*)nullptr, (float*)d_out);
    }
}